// Round 5
// baseline (369.788 us; speedup 1.0000x reference)
//
#include <hip/hip_runtime.h>
#include <hip/hip_fp16.h>
#include <math.h>

#define NN 100000
#define EE 1600000
#define DIN 128
#define C1 64   // HEADS*HID
#define C2 32   // D_OUT
#define NEG 0.2f

#define NB 1024   // coarse buckets
#define BSH 7     // bucket = dst >> 7 (128 nodes per bucket)
#define EPB 4096  // edges per binning block

static __device__ __forceinline__ float leaky(float x) { return x > 0.f ? x : NEG * x; }

// ---------------- CSR build: bucket-binned counting sort ----------------

__global__ __launch_bounds__(256) void k_chist(const int* __restrict__ ei, int* __restrict__ bhist) {
    __shared__ int h[NB];
    int t = threadIdx.x;
    for (int i = t; i < NB; i += 256) h[i] = 0;
    __syncthreads();
    int e0 = blockIdx.x * EPB;
#pragma unroll
    for (int j = 0; j < 16; j++) {
        int e = e0 + t + 256 * j;
        if (e < EE) atomicAdd(&h[ei[EE + e] >> BSH], 1);
    }
    __syncthreads();
    for (int i = t; i < NB; i += 256) {
        int c = h[i];
        if (c) atomicAdd(&bhist[i], c);
    }
}

__global__ __launch_bounds__(256) void k_bscan(const int* __restrict__ bhist,
                                               int* __restrict__ gbase, int* __restrict__ gcur) {
    __shared__ int s[256];
    int t = threadIdx.x;
    int base = t * 4;
    int v[4];
    int run = 0;
#pragma unroll
    for (int j = 0; j < 4; j++) {
        v[j] = run;
        run += bhist[base + j];
    }
    int val = run;
    s[t] = val;
    __syncthreads();
    for (int off = 1; off < 256; off <<= 1) {
        int add = (t >= off) ? s[t - off] : 0;
        __syncthreads();
        val += add;
        s[t] = val;
        __syncthreads();
    }
    int texcl = val - run;
#pragma unroll
    for (int j = 0; j < 4; j++) {
        gbase[base + j] = texcl + v[j];
        gcur[base + j] = texcl + v[j];
    }
}

__global__ __launch_bounds__(256) void k_bin(const int* __restrict__ ei, int* __restrict__ gcur,
                                             int2* __restrict__ binned) {
    __shared__ int h[NB];
    __shared__ int base[NB];
    int t = threadIdx.x;
    for (int i = t; i < NB; i += 256) h[i] = 0;
    __syncthreads();
    int e0 = blockIdx.x * EPB;
    int src[16], dst[16];
#pragma unroll
    for (int j = 0; j < 16; j++) {
        int e = e0 + t + 256 * j;
        if (e < EE) {
            src[j] = ei[e];
            dst[j] = ei[EE + e];
            atomicAdd(&h[dst[j] >> BSH], 1);
        } else
            dst[j] = -1;
    }
    __syncthreads();
    for (int i = t; i < NB; i += 256) {
        int c = h[i];
        if (c) base[i] = atomicAdd(&gcur[i], c);
        h[i] = 0;  // reuse as local cursor
    }
    __syncthreads();
#pragma unroll
    for (int j = 0; j < 16; j++) {
        if (dst[j] >= 0) {
            int b = dst[j] >> BSH;
            int r = atomicAdd(&h[b], 1);
            binned[base[b] + r] = make_int2(src[j], dst[j]);
        }
    }
}

// one block per bucket: counting sort of its edges; writes deg, rs, csr
__global__ __launch_bounds__(256) void k_bsort(const int2* __restrict__ binned,
                                               const int* __restrict__ gbase,
                                               const int* __restrict__ bhist,
                                               int* __restrict__ rs, int* __restrict__ deg,
                                               int* __restrict__ csr) {
    __shared__ int h[128], cur[128], sc[128];
    int b = blockIdx.x, t = threadIdx.x;
    if (t < 128) h[t] = 0;
    __syncthreads();
    int gb = gbase[b], cnt = bhist[b];
    for (int i = t; i < cnt; i += 256) atomicAdd(&h[binned[gb + i].y & 127], 1);
    __syncthreads();
    if (t < 128) sc[t] = h[t];
    __syncthreads();
    for (int off = 1; off < 128; off <<= 1) {
        int add = 0;
        if (t < 128 && t >= off) add = sc[t - off];
        __syncthreads();
        if (t < 128) sc[t] += add;
        __syncthreads();
    }
    if (t < 128) {
        int node = b * 128 + t;
        int excl = sc[t] - h[t];
        if (node < NN) {
            rs[node] = gb + excl;
            deg[node] = h[t];
        }
        cur[t] = excl;
    }
    __syncthreads();
    for (int i = t; i < cnt; i += 256) {
        int2 e = binned[gb + i];
        int r = atomicAdd(&cur[e.y & 127], 1);
        csr[gb + r] = e.x;
    }
}

// ---------------- GEMM1: h1 (fp16) = x @ W1, fused al_src/al_dst ----------------
__global__ __launch_bounds__(256, 2) void k_gemm1(
    const float* __restrict__ x, const float* __restrict__ W1,
    const float* __restrict__ a_s, const float* __restrict__ a_d,
    __half* __restrict__ h1h, float* __restrict__ als, float* __restrict__ ald) {
    __shared__ float xs[64 * 128];   // 32 KB
    __shared__ float wsh[128 * 64];  // 32 KB
    int t = threadIdx.x;
    int base = blockIdx.x * 64;
    for (int i = t; i < 2048; i += 256) ((float4*)wsh)[i] = ((const float4*)W1)[i];
    int maxn = NN - base;
    if (maxn > 64) maxn = 64;
    for (int i = t; i < 2048; i += 256) {
        int flat = i * 4;
        int n = flat >> 7;
        if (n < maxn) *(float4*)&xs[flat] = *(const float4*)&x[(size_t)(base + n) * 128 + (flat & 127)];
    }
    __syncthreads();
    int w = t >> 6, c = t & 63;
    int nb = w * 16;
    float acc[16];
#pragma unroll
    for (int j = 0; j < 16; j++) acc[j] = 0.f;
    for (int k = 0; k < 128; k += 4) {
        float w0 = wsh[k * 64 + c], w1 = wsh[(k + 1) * 64 + c];
        float w2 = wsh[(k + 2) * 64 + c], w3 = wsh[(k + 3) * 64 + c];
#pragma unroll
        for (int j = 0; j < 16; j++) {
            float4 xv = *(float4*)&xs[(nb + j) * 128 + k];
            acc[j] = fmaf(xv.x, w0, acc[j]);
            acc[j] = fmaf(xv.y, w1, acc[j]);
            acc[j] = fmaf(xv.z, w2, acc[j]);
            acc[j] = fmaf(xv.w, w3, acc[j]);
        }
    }
    float s_a = a_s[c], d_a = a_d[c];
    int hd = c >> 4;
#pragma unroll
    for (int j = 0; j < 16; j++) {
        int n = base + nb + j;
        float v = acc[j];
        float vs = v * s_a, vd = v * d_a;
#pragma unroll
        for (int off = 1; off < 16; off <<= 1) {
            vs += __shfl_xor(vs, off, 64);
            vd += __shfl_xor(vd, off, 64);
        }
        if (n < NN) {
            h1h[(size_t)n * 64 + c] = __float2half(v);
            if ((c & 15) == 0) {
                als[n * 4 + hd] = vs;
                ald[n * 4 + hd] = vd;
            }
        }
    }
}

// ---------------- Edge pass 1 + fused GEMM2 ----------------
// wave per dst node. Phase A: lane = edge, p = exp(logit - logit_self).
// Phase B: lane = (edge parity, channel pair); half2 gather, 2 edges/wave-iter.
__global__ __launch_bounds__(256) void k_edge1(
    const int* __restrict__ csr, const int* __restrict__ rs, const int* __restrict__ deg,
    const __half* __restrict__ h1h, const float* __restrict__ als, const float* __restrict__ ald,
    const float* __restrict__ b1, const float* __restrict__ W2,
    const float* __restrict__ as2, const float* __restrict__ ad2,
    __half* __restrict__ h2h, float* __restrict__ als2, float* __restrict__ ald2) {
    __shared__ float wsh[64 * 32];   // 8 KB: W2
    __shared__ float xld[4][64];     // per-wave x2 row
    __shared__ float pp[4][64][4];   // per-wave per-edge p[head]
    __shared__ int ss[4][64];        // per-wave per-edge src
    int t = threadIdx.x;
    for (int i = t; i < 512; i += 256) ((float4*)wsh)[i] = ((const float4*)W2)[i];
    int w = t >> 6, lane = t & 63;
    int n = blockIdx.x * 4 + w;  // NN % 4 == 0
    float4 ad4 = *(const float4*)&ald[n * 4];
    float4 an4 = *(const float4*)&als[n * 4];
    // self logits per head (wave-uniform shift; cancels in acc/z ratio)
    float ls0 = leaky(an4.x + ad4.x), ls1 = leaky(an4.y + ad4.y);
    float ls2 = leaky(an4.z + ad4.z), ls3 = leaky(an4.w + ad4.w);
    const __half2* h1p = (const __half2*)h1h;
    int cc = lane & 31, eh = lane >> 5;    // channel-pair, edge parity
    int hd2 = cc >> 3;                     // head of channels 2cc,2cc+1
    float z = 0.f, acc0 = 0.f, acc1 = 0.f;
    if (eh == 0) {                         // self contribution once
        float2 fs = __half22float2(h1p[n * 32 + cc]);
        z = 1.f;
        acc0 = fs.x;
        acc1 = fs.y;
    }
    int s0 = rs[n], d = deg[n];
    for (int i0 = 0; i0 < d; i0 += 64) {
        // phase A: lane = edge
        int e = i0 + lane;
        int src = 0;
        float4 a4 = make_float4(-1e30f, -1e30f, -1e30f, -1e30f);
        if (e < d) {
            src = csr[s0 + e];
            a4 = *(const float4*)&als[src * 4];
        }
        float p0 = __expf(leaky(a4.x + ad4.x) - ls0);
        float p1 = __expf(leaky(a4.y + ad4.y) - ls1);
        float p2 = __expf(leaky(a4.z + ad4.z) - ls2);
        float p3 = __expf(leaky(a4.w + ad4.w) - ls3);
        ss[w][lane] = src;
        *(float4*)&pp[w][lane][0] = make_float4(p0, p1, p2, p3);
        int cnt = d - i0;
        if (cnt > 64) cnt = 64;
        // phase B: 2 edges per iteration (half-waves interleave)
        for (int i = eh; i < cnt; i += 2) {
            int sA = ss[w][i];            // broadcast
            float pA = pp[w][i][hd2];     // bankwise broadcast
            float2 f = __half22float2(h1p[sA * 32 + cc]);
            z += pA;
            acc0 = fmaf(pA, f.x, acc0);
            acc1 = fmaf(pA, f.y, acc1);
        }
    }
    acc0 += __shfl_xor(acc0, 32, 64);
    acc1 += __shfl_xor(acc1, 32, 64);
    z += __shfl_xor(z, 32, 64);
    float zi = __frcp_rn(z + 1e-16f);
    float o0 = acc0 * zi + b1[2 * cc];
    float o1 = acc1 * zi + b1[2 * cc + 1];
    float xv0 = o0 > 0.f ? o0 : expm1f(o0);  // ELU
    float xv1 = o1 > 0.f ? o1 : expm1f(o1);
    if (eh == 0) {
        xld[w][2 * cc] = xv0;
        xld[w][2 * cc + 1] = xv1;
    }
    __syncthreads();  // covers wsh staging; xld is per-wave (in-order within wave)

    // ---- fused GEMM2: h2[n] = x2row @ W2 ----
    int hi = lane >> 5, c2 = lane & 31;
    float accn = 0.f;
#pragma unroll
    for (int k = 0; k < 32; k++) {
        float xk = xld[w][hi * 32 + k];
        accn = fmaf(xk, wsh[(hi * 32 + k) * 32 + c2], accn);
    }
    accn += __shfl_xor(accn, 32, 64);
    float vs = accn * as2[c2], vd = accn * ad2[c2];
#pragma unroll
    for (int off = 1; off < 32; off <<= 1) {
        vs += __shfl_xor(vs, off, 64);
        vd += __shfl_xor(vd, off, 64);
    }
    if (lane < 32) h2h[(size_t)n * 32 + lane] = __float2half(accn);
    if (lane == 0) {
        als2[n] = vs;
        ald2[n] = vd;
    }
}

// ---------------- Edge pass 2: wave per node; 16 half2-lanes/edge, 4 edges/iter ----------------
__global__ __launch_bounds__(256) void k_edge2(
    const int* __restrict__ csr, const int* __restrict__ rs, const int* __restrict__ deg,
    const __half* __restrict__ h2h, const float* __restrict__ als, const float* __restrict__ ald,
    const float* __restrict__ b2, float* __restrict__ out) {
    __shared__ float2 pst[4][64];  // {src, p}
    int t = threadIdx.x;
    int w = t >> 6, lane = t & 63;
    int n = blockIdx.x * 4 + w;  // NN % 4 == 0
    int cc = lane & 15, eq = lane >> 4;  // channel pair (16), edge quarter (4)
    float ad = ald[n];
    float lself = leaky(als[n] + ad);
    const __half2* h2p = (const __half2*)h2h;
    float z = 0.f, acc0 = 0.f, acc1 = 0.f;
    if (eq == 0) {
        float2 fs = __half22float2(h2p[n * 16 + cc]);
        z = 1.f;
        acc0 = fs.x;
        acc1 = fs.y;
    }
    int s0 = rs[n], d = deg[n];
    for (int i0 = 0; i0 < d; i0 += 64) {
        int e = i0 + lane;
        int src = 0;
        float av = -1e30f;
        if (e < d) {
            src = csr[s0 + e];
            av = als[src];
        }
        float p = __expf(leaky(av + ad) - lself);
        pst[w][lane] = make_float2(__int_as_float(src), p);
        int cnt = d - i0;
        if (cnt > 64) cnt = 64;
        for (int i = eq; i < cnt; i += 4) {  // quarters interleave over edges
            float2 q = pst[w][i];
            int sA = __float_as_int(q.x);
            float pA = q.y;
            float2 f = __half22float2(h2p[sA * 16 + cc]);
            z += pA;
            acc0 = fmaf(pA, f.x, acc0);
            acc1 = fmaf(pA, f.y, acc1);
        }
    }
    acc0 += __shfl_xor(acc0, 16, 64);
    acc0 += __shfl_xor(acc0, 32, 64);
    acc1 += __shfl_xor(acc1, 16, 64);
    acc1 += __shfl_xor(acc1, 32, 64);
    z += __shfl_xor(z, 16, 64);
    z += __shfl_xor(z, 32, 64);
    if (eq == 0) {
        float zi = __frcp_rn(z + 1e-16f);
        float o0 = acc0 * zi + b2[2 * cc];
        float o1 = acc1 * zi + b2[2 * cc + 1];
        *(float2*)&out[(size_t)n * 32 + 2 * cc] = make_float2(o0, o1);
    }
}

// ---------------- launcher ----------------
extern "C" void kernel_launch(void* const* d_in, const int* in_sizes, int n_in,
                              void* d_out, int out_size, void* d_ws, size_t ws_size,
                              hipStream_t stream) {
    const float* x = (const float*)d_in[0];
    const int* ei = (const int*)d_in[1];
    const float* W1 = (const float*)d_in[2];
    const float* as1 = (const float*)d_in[3];
    const float* ad1 = (const float*)d_in[4];
    const float* b1 = (const float*)d_in[5];
    const float* W2 = (const float*)d_in[6];
    const float* as2 = (const float*)d_in[7];
    const float* ad2 = (const float*)d_in[8];
    const float* b2 = (const float*)d_in[9];
    float* out = (float*)d_out;

    char* p = (char*)d_ws;
    auto alloc = [&](size_t bytes) -> char* {
        char* r = p;
        p += (bytes + 255) & ~(size_t)255;
        return r;
    };
    int* csr = (int*)alloc((size_t)EE * 4);
    int* rs = (int*)alloc((size_t)NN * 4);
    int* deg = (int*)alloc((size_t)NN * 4);
    int* bhist = (int*)alloc(NB * 4);
    int* gbase = (int*)alloc(NB * 4);
    int* gcur = (int*)alloc(NB * 4);
    __half* h1h = (__half*)alloc((size_t)NN * C1 * 2);
    float* als1 = (float*)alloc((size_t)NN * 4 * 4);
    float* ald1 = (float*)alloc((size_t)NN * 4 * 4);
    // region X: binned (12.8 MB) aliases h2h/als2/ald2 (7.2 MB); binned is dead
    // before k_edge1 writes h2h.
    char* regionX = alloc((size_t)EE * 8);
    int2* binned = (int2*)regionX;
    __half* h2h = (__half*)regionX;
    float* als2 = (float*)(regionX + (size_t)NN * C2 * 2);
    float* ald2 = (float*)(regionX + (size_t)NN * C2 * 2 + (size_t)NN * 4);
    (void)ws_size;

    hipMemsetAsync(bhist, 0, NB * 4, stream);

    int nbin = (EE + EPB - 1) / EPB;  // 391
    k_chist<<<nbin, 256, 0, stream>>>(ei, bhist);
    k_bscan<<<1, 256, 0, stream>>>(bhist, gbase, gcur);
    k_bin<<<nbin, 256, 0, stream>>>(ei, gcur, binned);
    k_bsort<<<(NN + 127) / 128, 256, 0, stream>>>(binned, gbase, bhist, rs, deg, csr);

    k_gemm1<<<(NN + 63) / 64, 256, 0, stream>>>(x, W1, as1, ad1, h1h, als1, ald1);
    k_edge1<<<NN / 4, 256, 0, stream>>>(csr, rs, deg, h1h, als1, ald1, b1, W2, as2, ad2,
                                        h2h, als2, ald2);
    k_edge2<<<NN / 4, 256, 0, stream>>>(csr, rs, deg, h2h, als2, ald2, b2, out);
}

// Round 6
// 340.834 us; speedup vs baseline: 1.0850x; 1.0850x over previous
//
#include <hip/hip_runtime.h>
#include <hip/hip_fp16.h>
#include <math.h>

#define NN 100000
#define EE 1600000
#define DIN 128
#define C1 64   // HEADS*HID
#define C2 32   // D_OUT
#define NEG 0.2f

#define NB 1024   // coarse buckets
#define BSH 7     // bucket = dst >> 7 (128 nodes per bucket)
#define EPB 4096  // edges per binning block

static __device__ __forceinline__ float leaky(float x) { return x > 0.f ? x : NEG * x; }

// ---------------- CSR build: bucket-binned counting sort ----------------

__global__ __launch_bounds__(256) void k_chist(const int* __restrict__ ei, int* __restrict__ bhist) {
    __shared__ int h[NB];
    int t = threadIdx.x;
    for (int i = t; i < NB; i += 256) h[i] = 0;
    __syncthreads();
    int e0 = blockIdx.x * EPB;
#pragma unroll
    for (int j = 0; j < 16; j++) {
        int e = e0 + t + 256 * j;
        if (e < EE) atomicAdd(&h[ei[EE + e] >> BSH], 1);
    }
    __syncthreads();
    for (int i = t; i < NB; i += 256) {
        int c = h[i];
        if (c) atomicAdd(&bhist[i], c);
    }
}

__global__ __launch_bounds__(256) void k_bscan(const int* __restrict__ bhist,
                                               int* __restrict__ gbase, int* __restrict__ gcur) {
    __shared__ int s[256];
    int t = threadIdx.x;
    int base = t * 4;
    int v[4];
    int run = 0;
#pragma unroll
    for (int j = 0; j < 4; j++) {
        v[j] = run;
        run += bhist[base + j];
    }
    int val = run;
    s[t] = val;
    __syncthreads();
    for (int off = 1; off < 256; off <<= 1) {
        int add = (t >= off) ? s[t - off] : 0;
        __syncthreads();
        val += add;
        s[t] = val;
        __syncthreads();
    }
    int texcl = val - run;
#pragma unroll
    for (int j = 0; j < 4; j++) {
        gbase[base + j] = texcl + v[j];
        gcur[base + j] = texcl + v[j];
    }
}

// binned entry: (src << 7) | (dst & 127)  -- src < 2^17, fits with room
__global__ __launch_bounds__(256) void k_bin(const int* __restrict__ ei, int* __restrict__ gcur,
                                             int* __restrict__ binned) {
    __shared__ int h[NB];
    __shared__ int base[NB];
    int t = threadIdx.x;
    for (int i = t; i < NB; i += 256) h[i] = 0;
    __syncthreads();
    int e0 = blockIdx.x * EPB;
    int src[16], dst[16];
#pragma unroll
    for (int j = 0; j < 16; j++) {
        int e = e0 + t + 256 * j;
        if (e < EE) {
            src[j] = ei[e];
            dst[j] = ei[EE + e];
            atomicAdd(&h[dst[j] >> BSH], 1);
        } else
            dst[j] = -1;
    }
    __syncthreads();
    for (int i = t; i < NB; i += 256) {
        int c = h[i];
        if (c) base[i] = atomicAdd(&gcur[i], c);
        h[i] = 0;  // reuse as local cursor
    }
    __syncthreads();
#pragma unroll
    for (int j = 0; j < 16; j++) {
        if (dst[j] >= 0) {
            int b = dst[j] >> BSH;
            int r = atomicAdd(&h[b], 1);
            binned[base[b] + r] = (src[j] << 7) | (dst[j] & 127);
        }
    }
}

// one block per bucket: counting sort of its edges; writes deg, rs, csr
__global__ __launch_bounds__(256) void k_bsort(const int* __restrict__ binned,
                                               const int* __restrict__ gbase,
                                               const int* __restrict__ bhist,
                                               int* __restrict__ rs, int* __restrict__ deg,
                                               int* __restrict__ csr) {
    __shared__ int h[128], cur[128], sc[128];
    int b = blockIdx.x, t = threadIdx.x;
    if (t < 128) h[t] = 0;
    __syncthreads();
    int gb = gbase[b], cnt = bhist[b];
    for (int i = t; i < cnt; i += 256) atomicAdd(&h[binned[gb + i] & 127], 1);
    __syncthreads();
    if (t < 128) sc[t] = h[t];
    __syncthreads();
    for (int off = 1; off < 128; off <<= 1) {
        int add = 0;
        if (t < 128 && t >= off) add = sc[t - off];
        __syncthreads();
        if (t < 128) sc[t] += add;
        __syncthreads();
    }
    if (t < 128) {
        int node = b * 128 + t;
        int excl = sc[t] - h[t];
        if (node < NN) {
            rs[node] = gb + excl;
            deg[node] = h[t];
        }
        cur[t] = excl;
    }
    __syncthreads();
    for (int i = t; i < cnt; i += 256) {
        int e = binned[gb + i];
        int r = atomicAdd(&cur[e & 127], 1);
        csr[gb + r] = e >> 7;
    }
}

// ---------------- GEMM1: h1 (fp16) = x @ W1, fused al_src/al_dst ----------------
__global__ __launch_bounds__(256, 2) void k_gemm1(
    const float* __restrict__ x, const float* __restrict__ W1,
    const float* __restrict__ a_s, const float* __restrict__ a_d,
    __half* __restrict__ h1h, float* __restrict__ als, float* __restrict__ ald) {
    __shared__ float xs[64 * 128];   // 32 KB
    __shared__ float wsh[128 * 64];  // 32 KB
    int t = threadIdx.x;
    int base = blockIdx.x * 64;
    for (int i = t; i < 2048; i += 256) ((float4*)wsh)[i] = ((const float4*)W1)[i];
    int maxn = NN - base;
    if (maxn > 64) maxn = 64;
    for (int i = t; i < 2048; i += 256) {
        int flat = i * 4;
        int n = flat >> 7;
        if (n < maxn) *(float4*)&xs[flat] = *(const float4*)&x[(size_t)(base + n) * 128 + (flat & 127)];
    }
    __syncthreads();
    int w = t >> 6, c = t & 63;
    int nb = w * 16;
    float acc[16];
#pragma unroll
    for (int j = 0; j < 16; j++) acc[j] = 0.f;
    for (int k = 0; k < 128; k += 4) {
        float w0 = wsh[k * 64 + c], w1 = wsh[(k + 1) * 64 + c];
        float w2 = wsh[(k + 2) * 64 + c], w3 = wsh[(k + 3) * 64 + c];
#pragma unroll
        for (int j = 0; j < 16; j++) {
            float4 xv = *(float4*)&xs[(nb + j) * 128 + k];
            acc[j] = fmaf(xv.x, w0, acc[j]);
            acc[j] = fmaf(xv.y, w1, acc[j]);
            acc[j] = fmaf(xv.z, w2, acc[j]);
            acc[j] = fmaf(xv.w, w3, acc[j]);
        }
    }
    float s_a = a_s[c], d_a = a_d[c];
    int hd = c >> 4;
#pragma unroll
    for (int j = 0; j < 16; j++) {
        int n = base + nb + j;
        float v = acc[j];
        float vs = v * s_a, vd = v * d_a;
#pragma unroll
        for (int off = 1; off < 16; off <<= 1) {
            vs += __shfl_xor(vs, off, 64);
            vd += __shfl_xor(vd, off, 64);
        }
        if (n < NN) {
            h1h[(size_t)n * 64 + c] = __float2half(v);
            if ((c & 15) == 0) {
                als[n * 4 + hd] = vs;
                ald[n * 4 + hd] = vd;
            }
        }
    }
}

// ---------------- Edge pass 1 + fused GEMM2 ----------------
// wave per dst node. Phase A: lane = edge, p = exp(logit - logit_self).
// Phase B: lane = (edge parity, channel pair); 4-deep batched half2 gathers.
__global__ __launch_bounds__(256) void k_edge1(
    const int* __restrict__ csr, const int* __restrict__ rs, const int* __restrict__ deg,
    const __half* __restrict__ h1h, const float* __restrict__ als, const float* __restrict__ ald,
    const float* __restrict__ b1, const float* __restrict__ W2,
    const float* __restrict__ as2, const float* __restrict__ ad2,
    __half* __restrict__ h2h, float* __restrict__ als2, float* __restrict__ ald2) {
    __shared__ float wsh[64 * 32];   // 8 KB: W2
    __shared__ float xld[4][64];     // per-wave x2 row
    __shared__ float pp[4][64][4];   // per-wave per-edge p[head]
    __shared__ int ss[4][64];        // per-wave per-edge src
    int t = threadIdx.x;
    for (int i = t; i < 512; i += 256) ((float4*)wsh)[i] = ((const float4*)W2)[i];
    int w = t >> 6, lane = t & 63;
    int n = blockIdx.x * 4 + w;  // NN % 4 == 0
    float4 ad4 = *(const float4*)&ald[n * 4];
    float4 an4 = *(const float4*)&als[n * 4];
    float ls0 = leaky(an4.x + ad4.x), ls1 = leaky(an4.y + ad4.y);
    float ls2 = leaky(an4.z + ad4.z), ls3 = leaky(an4.w + ad4.w);
    const __half2* h1p = (const __half2*)h1h;
    int cc = lane & 31, eh = lane >> 5;    // channel-pair, edge parity
    int hd2 = cc >> 3;                     // head of channels 2cc,2cc+1
    float z = 0.f, acc0 = 0.f, acc1 = 0.f;
    if (eh == 0) {                         // self contribution once
        float2 fs = __half22float2(h1p[n * 32 + cc]);
        z = 1.f;
        acc0 = fs.x;
        acc1 = fs.y;
    }
    int s0 = rs[n], d = deg[n];
    for (int i0 = 0; i0 < d; i0 += 64) {
        // phase A: lane = edge
        int e = i0 + lane;
        int src = 0;
        float4 a4 = make_float4(-1e30f, -1e30f, -1e30f, -1e30f);
        if (e < d) {
            src = csr[s0 + e];
            a4 = *(const float4*)&als[src * 4];
        }
        float p0 = __expf(leaky(a4.x + ad4.x) - ls0);
        float p1 = __expf(leaky(a4.y + ad4.y) - ls1);
        float p2 = __expf(leaky(a4.z + ad4.z) - ls2);
        float p3 = __expf(leaky(a4.w + ad4.w) - ls3);
        ss[w][lane] = src;
        *(float4*)&pp[w][lane][0] = make_float4(p0, p1, p2, p3);
        int cnt = d - i0;
        if (cnt > 64) cnt = 64;
        // phase B: 4-deep batched gathers (each half-wave strides by 2)
        int i = eh;
        for (; i + 6 < cnt; i += 8) {
            int sA = ss[w][i], sB = ss[w][i + 2], sC = ss[w][i + 4], sD = ss[w][i + 6];
            float pA = pp[w][i][hd2], pB = pp[w][i + 2][hd2];
            float pC = pp[w][i + 4][hd2], pD = pp[w][i + 6][hd2];
            float2 fA = __half22float2(h1p[sA * 32 + cc]);
            float2 fB = __half22float2(h1p[sB * 32 + cc]);
            float2 fC = __half22float2(h1p[sC * 32 + cc]);
            float2 fD = __half22float2(h1p[sD * 32 + cc]);
            z += (pA + pB) + (pC + pD);
            acc0 = fmaf(pA, fA.x, acc0);
            acc1 = fmaf(pA, fA.y, acc1);
            acc0 = fmaf(pB, fB.x, acc0);
            acc1 = fmaf(pB, fB.y, acc1);
            acc0 = fmaf(pC, fC.x, acc0);
            acc1 = fmaf(pC, fC.y, acc1);
            acc0 = fmaf(pD, fD.x, acc0);
            acc1 = fmaf(pD, fD.y, acc1);
        }
        for (; i < cnt; i += 2) {
            int sA = ss[w][i];
            float pA = pp[w][i][hd2];
            float2 f = __half22float2(h1p[sA * 32 + cc]);
            z += pA;
            acc0 = fmaf(pA, f.x, acc0);
            acc1 = fmaf(pA, f.y, acc1);
        }
    }
    acc0 += __shfl_xor(acc0, 32, 64);
    acc1 += __shfl_xor(acc1, 32, 64);
    z += __shfl_xor(z, 32, 64);
    float zi = __frcp_rn(z + 1e-16f);
    float o0 = acc0 * zi + b1[2 * cc];
    float o1 = acc1 * zi + b1[2 * cc + 1];
    float xv0 = o0 > 0.f ? o0 : expm1f(o0);  // ELU
    float xv1 = o1 > 0.f ? o1 : expm1f(o1);
    if (eh == 0) {
        xld[w][2 * cc] = xv0;
        xld[w][2 * cc + 1] = xv1;
    }
    __syncthreads();  // covers wsh staging; xld is per-wave (lockstep within wave)

    // ---- fused GEMM2: h2[n] = x2row @ W2 ----
    int hi = lane >> 5, c2 = lane & 31;
    float accn = 0.f;
#pragma unroll
    for (int k = 0; k < 32; k++) {
        float xk = xld[w][hi * 32 + k];
        accn = fmaf(xk, wsh[(hi * 32 + k) * 32 + c2], accn);
    }
    accn += __shfl_xor(accn, 32, 64);
    float vs = accn * as2[c2], vd = accn * ad2[c2];
#pragma unroll
    for (int off = 1; off < 32; off <<= 1) {
        vs += __shfl_xor(vs, off, 64);
        vd += __shfl_xor(vd, off, 64);
    }
    if (lane < 32) h2h[(size_t)n * 32 + lane] = __float2half(accn);
    if (lane == 0) {
        als2[n] = vs;
        ald2[n] = vd;
    }
}

// ---------------- Edge pass 2: wave per node; 16 half2-lanes/edge, 4 edges/iter ----------------
__global__ __launch_bounds__(256) void k_edge2(
    const int* __restrict__ csr, const int* __restrict__ rs, const int* __restrict__ deg,
    const __half* __restrict__ h2h, const float* __restrict__ als, const float* __restrict__ ald,
    const float* __restrict__ b2, float* __restrict__ out) {
    __shared__ float2 pst[4][64];  // {src, p}
    int t = threadIdx.x;
    int w = t >> 6, lane = t & 63;
    int n = blockIdx.x * 4 + w;  // NN % 4 == 0
    int cc = lane & 15, eq = lane >> 4;  // channel pair (16), edge quarter (4)
    float ad = ald[n];
    float lself = leaky(als[n] + ad);
    const __half2* h2p = (const __half2*)h2h;
    float z = 0.f, acc0 = 0.f, acc1 = 0.f;
    if (eq == 0) {
        float2 fs = __half22float2(h2p[n * 16 + cc]);
        z = 1.f;
        acc0 = fs.x;
        acc1 = fs.y;
    }
    int s0 = rs[n], d = deg[n];
    for (int i0 = 0; i0 < d; i0 += 64) {
        int e = i0 + lane;
        int src = 0;
        float av = -1e30f;
        if (e < d) {
            src = csr[s0 + e];
            av = als[src];
        }
        float p = __expf(leaky(av + ad) - lself);
        pst[w][lane] = make_float2(__int_as_float(src), p);
        int cnt = d - i0;
        if (cnt > 64) cnt = 64;
        // 4-deep batched gathers (each quarter-wave strides by 4)
        int i = eq;
        for (; i + 12 < cnt; i += 16) {
            float2 qA = pst[w][i], qB = pst[w][i + 4], qC = pst[w][i + 8], qD = pst[w][i + 12];
            int sA = __float_as_int(qA.x), sB = __float_as_int(qB.x);
            int sC = __float_as_int(qC.x), sD = __float_as_int(qD.x);
            float2 fA = __half22float2(h2p[sA * 16 + cc]);
            float2 fB = __half22float2(h2p[sB * 16 + cc]);
            float2 fC = __half22float2(h2p[sC * 16 + cc]);
            float2 fD = __half22float2(h2p[sD * 16 + cc]);
            z += (qA.y + qB.y) + (qC.y + qD.y);
            acc0 = fmaf(qA.y, fA.x, acc0);
            acc1 = fmaf(qA.y, fA.y, acc1);
            acc0 = fmaf(qB.y, fB.x, acc0);
            acc1 = fmaf(qB.y, fB.y, acc1);
            acc0 = fmaf(qC.y, fC.x, acc0);
            acc1 = fmaf(qC.y, fC.y, acc1);
            acc0 = fmaf(qD.y, fD.x, acc0);
            acc1 = fmaf(qD.y, fD.y, acc1);
        }
        for (; i < cnt; i += 4) {
            float2 q = pst[w][i];
            int sA = __float_as_int(q.x);
            float pA = q.y;
            float2 f = __half22float2(h2p[sA * 16 + cc]);
            z += pA;
            acc0 = fmaf(pA, f.x, acc0);
            acc1 = fmaf(pA, f.y, acc1);
        }
    }
    acc0 += __shfl_xor(acc0, 16, 64);
    acc0 += __shfl_xor(acc0, 32, 64);
    acc1 += __shfl_xor(acc1, 16, 64);
    acc1 += __shfl_xor(acc1, 32, 64);
    z += __shfl_xor(z, 16, 64);
    z += __shfl_xor(z, 32, 64);
    if (eq == 0) {
        float zi = __frcp_rn(z + 1e-16f);
        float o0 = acc0 * zi + b2[2 * cc];
        float o1 = acc1 * zi + b2[2 * cc + 1];
        *(float2*)&out[(size_t)n * 32 + 2 * cc] = make_float2(o0, o1);
    }
}

// ---------------- launcher ----------------
extern "C" void kernel_launch(void* const* d_in, const int* in_sizes, int n_in,
                              void* d_out, int out_size, void* d_ws, size_t ws_size,
                              hipStream_t stream) {
    const float* x = (const float*)d_in[0];
    const int* ei = (const int*)d_in[1];
    const float* W1 = (const float*)d_in[2];
    const float* as1 = (const float*)d_in[3];
    const float* ad1 = (const float*)d_in[4];
    const float* b1 = (const float*)d_in[5];
    const float* W2 = (const float*)d_in[6];
    const float* as2 = (const float*)d_in[7];
    const float* ad2 = (const float*)d_in[8];
    const float* b2 = (const float*)d_in[9];
    float* out = (float*)d_out;

    char* p = (char*)d_ws;
    auto alloc = [&](size_t bytes) -> char* {
        char* r = p;
        p += (bytes + 255) & ~(size_t)255;
        return r;
    };
    int* csr = (int*)alloc((size_t)EE * 4);
    int* rs = (int*)alloc((size_t)NN * 4);
    int* deg = (int*)alloc((size_t)NN * 4);
    int* bhist = (int*)alloc(NB * 4);
    int* gbase = (int*)alloc(NB * 4);
    int* gcur = (int*)alloc(NB * 4);
    __half* h1h = (__half*)alloc((size_t)NN * C1 * 2);
    float* als1 = (float*)alloc((size_t)NN * 4 * 4);
    float* ald1 = (float*)alloc((size_t)NN * 4 * 4);
    // region X: binned (6.4 MB) aliases h2h/als2/ald2 (7.2 MB); binned is dead
    // before k_edge1 writes h2h.
    char* regionX = alloc((size_t)NN * C2 * 2 + (size_t)NN * 8 + 512);
    int* binned = (int*)regionX;
    __half* h2h = (__half*)regionX;
    float* als2 = (float*)(regionX + (size_t)NN * C2 * 2);
    float* ald2 = (float*)(regionX + (size_t)NN * C2 * 2 + (size_t)NN * 4);
    (void)ws_size;

    hipMemsetAsync(bhist, 0, NB * 4, stream);

    int nbin = (EE + EPB - 1) / EPB;  // 391
    k_chist<<<nbin, 256, 0, stream>>>(ei, bhist);
    k_bscan<<<1, 256, 0, stream>>>(bhist, gbase, gcur);
    k_bin<<<nbin, 256, 0, stream>>>(ei, gcur, binned);
    k_bsort<<<(NN + 127) / 128, 256, 0, stream>>>(binned, gbase, bhist, rs, deg, csr);

    k_gemm1<<<(NN + 63) / 64, 256, 0, stream>>>(x, W1, as1, ad1, h1h, als1, ald1);
    k_edge1<<<NN / 4, 256, 0, stream>>>(csr, rs, deg, h1h, als1, ald1, b1, W2, as2, ad2,
                                        h2h, als2, ald2);
    k_edge2<<<NN / 4, 256, 0, stream>>>(csr, rs, deg, h2h, als2, ald2, b2, out);
}

// Round 7
// 332.312 us; speedup vs baseline: 1.1128x; 1.0256x over previous
//
#include <hip/hip_runtime.h>
#include <hip/hip_fp16.h>
#include <math.h>

#define NN 100000
#define EE 1600000
#define DIN 128
#define C1 64   // HEADS*HID
#define C2 32   // D_OUT
#define NEG 0.2f

#define NB 1024   // coarse buckets
#define BSH 7     // bucket = dst >> 7 (128 nodes per bucket)
#define EPB 4096  // edges per binning block
#define NGEMM 1563   // ceil(NN/64)
#define NCHIST 391   // ceil(EE/EPB)

static __device__ __forceinline__ float leaky(float x) { return fmaxf(x, NEG * x); }

// ---------------- fused GEMM1 + coarse histogram ----------------
// blocks [0, NGEMM): h1 (fp16) = x @ W1 with fused al_src/al_dst
// blocks [NGEMM, NGEMM+NCHIST): bucket histogram of dst (independent work,
// hidden under gemm1 instead of serialized before it)
__global__ __launch_bounds__(256, 2) void k_gemm1_chist(
    const float* __restrict__ x, const float* __restrict__ W1,
    const float* __restrict__ a_s, const float* __restrict__ a_d,
    __half* __restrict__ h1h, float* __restrict__ als, float* __restrict__ ald,
    const int* __restrict__ ei, int* __restrict__ bhist) {
    __shared__ float xs[64 * 128];   // 32 KB
    __shared__ float wsh[128 * 64];  // 32 KB
    int t = threadIdx.x;
    if (blockIdx.x >= NGEMM) {
        // ---- chist branch (reuses xs as int histogram) ----
        int* h = (int*)xs;
        for (int i = t; i < NB; i += 256) h[i] = 0;
        __syncthreads();
        const int4* d4p = (const int4*)(ei + EE);
        int i40 = (blockIdx.x - NGEMM) * (EPB / 4);
#pragma unroll
        for (int j = 0; j < 4; j++) {
            int idx = i40 + t + 256 * j;
            if (idx < EE / 4) {
                int4 d4 = d4p[idx];
                atomicAdd(&h[d4.x >> BSH], 1);
                atomicAdd(&h[d4.y >> BSH], 1);
                atomicAdd(&h[d4.z >> BSH], 1);
                atomicAdd(&h[d4.w >> BSH], 1);
            }
        }
        __syncthreads();
        for (int i = t; i < NB; i += 256) {
            int c = h[i];
            if (c) atomicAdd(&bhist[i], c);
        }
        return;
    }
    // ---- gemm1 branch ----
    int base = blockIdx.x * 64;
    for (int i = t; i < 2048; i += 256) ((float4*)wsh)[i] = ((const float4*)W1)[i];
    int maxn = NN - base;
    if (maxn > 64) maxn = 64;
    for (int i = t; i < 2048; i += 256) {
        int flat = i * 4;
        int n = flat >> 7;
        if (n < maxn) *(float4*)&xs[flat] = *(const float4*)&x[(size_t)(base + n) * 128 + (flat & 127)];
    }
    __syncthreads();
    int w = t >> 6, c = t & 63;
    int nb = w * 16;
    float acc[16];
#pragma unroll
    for (int j = 0; j < 16; j++) acc[j] = 0.f;
    for (int k = 0; k < 128; k += 4) {
        float w0 = wsh[k * 64 + c], w1 = wsh[(k + 1) * 64 + c];
        float w2 = wsh[(k + 2) * 64 + c], w3 = wsh[(k + 3) * 64 + c];
#pragma unroll
        for (int j = 0; j < 16; j++) {
            float4 xv = *(float4*)&xs[(nb + j) * 128 + k];
            acc[j] = fmaf(xv.x, w0, acc[j]);
            acc[j] = fmaf(xv.y, w1, acc[j]);
            acc[j] = fmaf(xv.z, w2, acc[j]);
            acc[j] = fmaf(xv.w, w3, acc[j]);
        }
    }
    float s_a = a_s[c], d_a = a_d[c];
    int hd = c >> 4;
#pragma unroll
    for (int j = 0; j < 16; j++) {
        int n = base + nb + j;
        float v = acc[j];
        float vs = v * s_a, vd = v * d_a;
#pragma unroll
        for (int off = 1; off < 16; off <<= 1) {
            vs += __shfl_xor(vs, off, 64);
            vd += __shfl_xor(vd, off, 64);
        }
        if (n < NN) {
            h1h[(size_t)n * 64 + c] = __float2half(v);
            if ((c & 15) == 0) {
                als[n * 4 + hd] = vs;
                ald[n * 4 + hd] = vd;
            }
        }
    }
}

// ---------------- rest of CSR build ----------------

__global__ __launch_bounds__(256) void k_bscan(const int* __restrict__ bhist,
                                               int* __restrict__ gbase, int* __restrict__ gcur) {
    __shared__ int s[256];
    int t = threadIdx.x;
    int base = t * 4;
    int v[4];
    int run = 0;
#pragma unroll
    for (int j = 0; j < 4; j++) {
        v[j] = run;
        run += bhist[base + j];
    }
    int val = run;
    s[t] = val;
    __syncthreads();
    for (int off = 1; off < 256; off <<= 1) {
        int add = (t >= off) ? s[t - off] : 0;
        __syncthreads();
        val += add;
        s[t] = val;
        __syncthreads();
    }
    int texcl = val - run;
#pragma unroll
    for (int j = 0; j < 4; j++) {
        gbase[base + j] = texcl + v[j];
        gcur[base + j] = texcl + v[j];
    }
}

// binned entry: (src << 7) | (dst & 127)
__global__ __launch_bounds__(256) void k_bin(const int* __restrict__ ei, int* __restrict__ gcur,
                                             int* __restrict__ binned) {
    __shared__ int h[NB];
    __shared__ int base[NB];
    int t = threadIdx.x;
    for (int i = t; i < NB; i += 256) h[i] = 0;
    __syncthreads();
    const int4* s4p = (const int4*)ei;
    const int4* d4p = (const int4*)(ei + EE);
    int i40 = blockIdx.x * (EPB / 4);
    int4 s4[4], d4[4];
    bool val[4];
#pragma unroll
    for (int j = 0; j < 4; j++) {
        int idx = i40 + t + 256 * j;
        val[j] = idx < EE / 4;
        if (val[j]) {
            s4[j] = s4p[idx];
            d4[j] = d4p[idx];
            atomicAdd(&h[d4[j].x >> BSH], 1);
            atomicAdd(&h[d4[j].y >> BSH], 1);
            atomicAdd(&h[d4[j].z >> BSH], 1);
            atomicAdd(&h[d4[j].w >> BSH], 1);
        }
    }
    __syncthreads();
    for (int i = t; i < NB; i += 256) {
        int c = h[i];
        if (c) base[i] = atomicAdd(&gcur[i], c);
        h[i] = 0;  // reuse as local cursor
    }
    __syncthreads();
#pragma unroll
    for (int j = 0; j < 4; j++) {
        if (val[j]) {
            int ss[4] = {s4[j].x, s4[j].y, s4[j].z, s4[j].w};
            int dd[4] = {d4[j].x, d4[j].y, d4[j].z, d4[j].w};
#pragma unroll
            for (int q = 0; q < 4; q++) {
                int b = dd[q] >> BSH;
                int r = atomicAdd(&h[b], 1);
                binned[base[b] + r] = (ss[q] << 7) | (dd[q] & 127);
            }
        }
    }
}

// one block per bucket: counting sort of its edges; writes deg, rs, csr
__global__ __launch_bounds__(256) void k_bsort(const int* __restrict__ binned,
                                               const int* __restrict__ gbase,
                                               const int* __restrict__ bhist,
                                               int* __restrict__ rs, int* __restrict__ deg,
                                               int* __restrict__ csr) {
    __shared__ int h[128], cur[128], sc[128];
    int b = blockIdx.x, t = threadIdx.x;
    if (t < 128) h[t] = 0;
    __syncthreads();
    int gb = gbase[b], cnt = bhist[b];
    for (int i = t; i < cnt; i += 256) atomicAdd(&h[binned[gb + i] & 127], 1);
    __syncthreads();
    if (t < 128) sc[t] = h[t];
    __syncthreads();
    for (int off = 1; off < 128; off <<= 1) {
        int add = 0;
        if (t < 128 && t >= off) add = sc[t - off];
        __syncthreads();
        if (t < 128) sc[t] += add;
        __syncthreads();
    }
    if (t < 128) {
        int node = b * 128 + t;
        int excl = sc[t] - h[t];
        if (node < NN) {
            rs[node] = gb + excl;
            deg[node] = h[t];
        }
        cur[t] = excl;
    }
    __syncthreads();
    for (int i = t; i < cnt; i += 256) {
        int e = binned[gb + i];
        int r = atomicAdd(&cur[e & 127], 1);
        csr[gb + r] = e >> 7;
    }
}

// ---------------- Edge pass 1 + fused GEMM2 ----------------
// wave per dst node. Phase A: lane = edge; stores (src,p) per head as float2.
// Phase B: lane = (edge parity, channel pair); single b64 LDS read per edge,
// 8-deep batched half2 gathers.
__global__ __launch_bounds__(256, 4) void k_edge1(
    const int* __restrict__ csr, const int* __restrict__ rs, const int* __restrict__ deg,
    const __half* __restrict__ h1h, const float* __restrict__ als, const float* __restrict__ ald,
    const float* __restrict__ b1, const float* __restrict__ W2,
    const float* __restrict__ as2, const float* __restrict__ ad2,
    __half* __restrict__ h2h, float* __restrict__ als2, float* __restrict__ ald2) {
    __shared__ float wsh[64 * 32];      // 8 KB: W2
    __shared__ float xld[4][64];        // per-wave x2 row
    __shared__ float2 epl[4][4][65];    // [wave][head][edge(+pad)]: {src, p}
    int t = threadIdx.x;
    for (int i = t; i < 512; i += 256) ((float4*)wsh)[i] = ((const float4*)W2)[i];
    int w = t >> 6, lane = t & 63;
    int n = blockIdx.x * 4 + w;  // NN % 4 == 0
    float4 ad4 = *(const float4*)&ald[n * 4];
    float4 an4 = *(const float4*)&als[n * 4];
    float ls0 = leaky(an4.x + ad4.x), ls1 = leaky(an4.y + ad4.y);
    float ls2 = leaky(an4.z + ad4.z), ls3 = leaky(an4.w + ad4.w);
    const __half2* h1p = (const __half2*)h1h;
    int cc = lane & 31, eh = lane >> 5;    // channel-pair, edge parity
    int hd2 = cc >> 3;                     // head of channels 2cc,2cc+1
    float z = 0.f, acc0 = 0.f, acc1 = 0.f;
    if (eh == 0) {                         // self contribution once
        float2 fs = __half22float2(h1p[n * 32 + cc]);
        z = 1.f;
        acc0 = fs.x;
        acc1 = fs.y;
    }
    int s0 = rs[n], d = deg[n];
    for (int i0 = 0; i0 < d; i0 += 64) {
        // phase A: lane = edge
        int e = i0 + lane;
        int src = 0;
        float4 a4 = make_float4(-1e30f, -1e30f, -1e30f, -1e30f);
        if (e < d) {
            src = csr[s0 + e];
            a4 = *(const float4*)&als[src * 4];
        }
        float fsrc = __int_as_float(src);
        epl[w][0][lane] = make_float2(fsrc, __expf(leaky(a4.x + ad4.x) - ls0));
        epl[w][1][lane] = make_float2(fsrc, __expf(leaky(a4.y + ad4.y) - ls1));
        epl[w][2][lane] = make_float2(fsrc, __expf(leaky(a4.z + ad4.z) - ls2));
        epl[w][3][lane] = make_float2(fsrc, __expf(leaky(a4.w + ad4.w) - ls3));
        int cnt = d - i0;
        if (cnt > 64) cnt = 64;
        // phase B (each half-wave strides by 2 over edges)
        int i = eh;
        for (; i + 14 < cnt; i += 16) {  // 8-deep
            float2 q0 = epl[w][hd2][i], q1 = epl[w][hd2][i + 2];
            float2 q2 = epl[w][hd2][i + 4], q3 = epl[w][hd2][i + 6];
            float2 q4 = epl[w][hd2][i + 8], q5 = epl[w][hd2][i + 10];
            float2 q6 = epl[w][hd2][i + 12], q7 = epl[w][hd2][i + 14];
            float2 f0 = __half22float2(h1p[__float_as_int(q0.x) * 32 + cc]);
            float2 f1 = __half22float2(h1p[__float_as_int(q1.x) * 32 + cc]);
            float2 f2 = __half22float2(h1p[__float_as_int(q2.x) * 32 + cc]);
            float2 f3 = __half22float2(h1p[__float_as_int(q3.x) * 32 + cc]);
            float2 f4 = __half22float2(h1p[__float_as_int(q4.x) * 32 + cc]);
            float2 f5 = __half22float2(h1p[__float_as_int(q5.x) * 32 + cc]);
            float2 f6 = __half22float2(h1p[__float_as_int(q6.x) * 32 + cc]);
            float2 f7 = __half22float2(h1p[__float_as_int(q7.x) * 32 + cc]);
            z += ((q0.y + q1.y) + (q2.y + q3.y)) + ((q4.y + q5.y) + (q6.y + q7.y));
            acc0 = fmaf(q0.y, f0.x, acc0); acc1 = fmaf(q0.y, f0.y, acc1);
            acc0 = fmaf(q1.y, f1.x, acc0); acc1 = fmaf(q1.y, f1.y, acc1);
            acc0 = fmaf(q2.y, f2.x, acc0); acc1 = fmaf(q2.y, f2.y, acc1);
            acc0 = fmaf(q3.y, f3.x, acc0); acc1 = fmaf(q3.y, f3.y, acc1);
            acc0 = fmaf(q4.y, f4.x, acc0); acc1 = fmaf(q4.y, f4.y, acc1);
            acc0 = fmaf(q5.y, f5.x, acc0); acc1 = fmaf(q5.y, f5.y, acc1);
            acc0 = fmaf(q6.y, f6.x, acc0); acc1 = fmaf(q6.y, f6.y, acc1);
            acc0 = fmaf(q7.y, f7.x, acc0); acc1 = fmaf(q7.y, f7.y, acc1);
        }
        for (; i + 6 < cnt; i += 8) {  // 4-deep
            float2 q0 = epl[w][hd2][i], q1 = epl[w][hd2][i + 2];
            float2 q2 = epl[w][hd2][i + 4], q3 = epl[w][hd2][i + 6];
            float2 f0 = __half22float2(h1p[__float_as_int(q0.x) * 32 + cc]);
            float2 f1 = __half22float2(h1p[__float_as_int(q1.x) * 32 + cc]);
            float2 f2 = __half22float2(h1p[__float_as_int(q2.x) * 32 + cc]);
            float2 f3 = __half22float2(h1p[__float_as_int(q3.x) * 32 + cc]);
            z += (q0.y + q1.y) + (q2.y + q3.y);
            acc0 = fmaf(q0.y, f0.x, acc0); acc1 = fmaf(q0.y, f0.y, acc1);
            acc0 = fmaf(q1.y, f1.x, acc0); acc1 = fmaf(q1.y, f1.y, acc1);
            acc0 = fmaf(q2.y, f2.x, acc0); acc1 = fmaf(q2.y, f2.y, acc1);
            acc0 = fmaf(q3.y, f3.x, acc0); acc1 = fmaf(q3.y, f3.y, acc1);
        }
        for (; i < cnt; i += 2) {
            float2 q = epl[w][hd2][i];
            float2 f = __half22float2(h1p[__float_as_int(q.x) * 32 + cc]);
            z += q.y;
            acc0 = fmaf(q.y, f.x, acc0);
            acc1 = fmaf(q.y, f.y, acc1);
        }
    }
    acc0 += __shfl_xor(acc0, 32, 64);
    acc1 += __shfl_xor(acc1, 32, 64);
    z += __shfl_xor(z, 32, 64);
    float zi = __frcp_rn(z + 1e-16f);
    float o0 = acc0 * zi + b1[2 * cc];
    float o1 = acc1 * zi + b1[2 * cc + 1];
    float xv0 = o0 > 0.f ? o0 : __expf(o0) - 1.f;  // ELU (fp32-safe form)
    float xv1 = o1 > 0.f ? o1 : __expf(o1) - 1.f;
    if (eh == 0) {
        xld[w][2 * cc] = xv0;
        xld[w][2 * cc + 1] = xv1;
    }
    __syncthreads();  // covers wsh staging; xld is wave-private (lockstep)

    // ---- fused GEMM2: h2[n] = x2row @ W2 ----
    int hi = lane >> 5, c2 = lane & 31;
    float accn = 0.f;
#pragma unroll
    for (int k = 0; k < 32; k++) {
        float xk = xld[w][hi * 32 + k];
        accn = fmaf(xk, wsh[(hi * 32 + k) * 32 + c2], accn);
    }
    accn += __shfl_xor(accn, 32, 64);
    float vs = accn * as2[c2], vd = accn * ad2[c2];
#pragma unroll
    for (int off = 1; off < 32; off <<= 1) {
        vs += __shfl_xor(vs, off, 64);
        vd += __shfl_xor(vd, off, 64);
    }
    if (lane < 32) h2h[(size_t)n * 32 + lane] = __float2half(accn);
    if (lane == 0) {
        als2[n] = vs;
        ald2[n] = vd;
    }
}

// ---------------- Edge pass 2: wave per node; 16 half2-lanes/edge, 4 edges/iter ----------------
__global__ __launch_bounds__(256, 4) void k_edge2(
    const int* __restrict__ csr, const int* __restrict__ rs, const int* __restrict__ deg,
    const __half* __restrict__ h2h, const float* __restrict__ als, const float* __restrict__ ald,
    const float* __restrict__ b2, float* __restrict__ out) {
    __shared__ float2 pst[4][64];  // {src, p}
    int t = threadIdx.x;
    int w = t >> 6, lane = t & 63;
    int n = blockIdx.x * 4 + w;  // NN % 4 == 0
    int cc = lane & 15, eq = lane >> 4;  // channel pair (16), edge quarter (4)
    float ad = ald[n];
    float lself = leaky(als[n] + ad);
    const __half2* h2p = (const __half2*)h2h;
    float z = 0.f, acc0 = 0.f, acc1 = 0.f;
    if (eq == 0) {
        float2 fs = __half22float2(h2p[n * 16 + cc]);
        z = 1.f;
        acc0 = fs.x;
        acc1 = fs.y;
    }
    int s0 = rs[n], d = deg[n];
    for (int i0 = 0; i0 < d; i0 += 64) {
        int e = i0 + lane;
        int src = 0;
        float av = -1e30f;
        if (e < d) {
            src = csr[s0 + e];
            av = als[src];
        }
        float p = __expf(leaky(av + ad) - lself);
        pst[w][lane] = make_float2(__int_as_float(src), p);
        int cnt = d - i0;
        if (cnt > 64) cnt = 64;
        int i = eq;
        for (; i + 12 < cnt; i += 16) {  // 4-deep (quarters stride 4)
            float2 qA = pst[w][i], qB = pst[w][i + 4], qC = pst[w][i + 8], qD = pst[w][i + 12];
            int sA = __float_as_int(qA.x), sB = __float_as_int(qB.x);
            int sC = __float_as_int(qC.x), sD = __float_as_int(qD.x);
            float2 fA = __half22float2(h2p[sA * 16 + cc]);
            float2 fB = __half22float2(h2p[sB * 16 + cc]);
            float2 fC = __half22float2(h2p[sC * 16 + cc]);
            float2 fD = __half22float2(h2p[sD * 16 + cc]);
            z += (qA.y + qB.y) + (qC.y + qD.y);
            acc0 = fmaf(qA.y, fA.x, acc0); acc1 = fmaf(qA.y, fA.y, acc1);
            acc0 = fmaf(qB.y, fB.x, acc0); acc1 = fmaf(qB.y, fB.y, acc1);
            acc0 = fmaf(qC.y, fC.x, acc0); acc1 = fmaf(qC.y, fC.y, acc1);
            acc0 = fmaf(qD.y, fD.x, acc0); acc1 = fmaf(qD.y, fD.y, acc1);
        }
        for (; i < cnt; i += 4) {
            float2 q = pst[w][i];
            int sA = __float_as_int(q.x);
            float pA = q.y;
            float2 f = __half22float2(h2p[sA * 16 + cc]);
            z += pA;
            acc0 = fmaf(pA, f.x, acc0);
            acc1 = fmaf(pA, f.y, acc1);
        }
    }
    acc0 += __shfl_xor(acc0, 16, 64);
    acc0 += __shfl_xor(acc0, 32, 64);
    acc1 += __shfl_xor(acc1, 16, 64);
    acc1 += __shfl_xor(acc1, 32, 64);
    z += __shfl_xor(z, 16, 64);
    z += __shfl_xor(z, 32, 64);
    if (eq == 0) {
        float zi = __frcp_rn(z + 1e-16f);
        float o0 = acc0 * zi + b2[2 * cc];
        float o1 = acc1 * zi + b2[2 * cc + 1];
        *(float2*)&out[(size_t)n * 32 + 2 * cc] = make_float2(o0, o1);
    }
}

// ---------------- launcher ----------------
extern "C" void kernel_launch(void* const* d_in, const int* in_sizes, int n_in,
                              void* d_out, int out_size, void* d_ws, size_t ws_size,
                              hipStream_t stream) {
    const float* x = (const float*)d_in[0];
    const int* ei = (const int*)d_in[1];
    const float* W1 = (const float*)d_in[2];
    const float* as1 = (const float*)d_in[3];
    const float* ad1 = (const float*)d_in[4];
    const float* b1 = (const float*)d_in[5];
    const float* W2 = (const float*)d_in[6];
    const float* as2 = (const float*)d_in[7];
    const float* ad2 = (const float*)d_in[8];
    const float* b2 = (const float*)d_in[9];
    float* out = (float*)d_out;

    char* p = (char*)d_ws;
    auto alloc = [&](size_t bytes) -> char* {
        char* r = p;
        p += (bytes + 255) & ~(size_t)255;
        return r;
    };
    int* csr = (int*)alloc((size_t)EE * 4);
    int* rs = (int*)alloc((size_t)NN * 4);
    int* deg = (int*)alloc((size_t)NN * 4);
    int* bhist = (int*)alloc(NB * 4);
    int* gbase = (int*)alloc(NB * 4);
    int* gcur = (int*)alloc(NB * 4);
    __half* h1h = (__half*)alloc((size_t)NN * C1 * 2);
    float* als1 = (float*)alloc((size_t)NN * 4 * 4);
    float* ald1 = (float*)alloc((size_t)NN * 4 * 4);
    // region X: binned (6.4 MB) aliases h2h/als2/ald2 (7.2 MB); binned is dead
    // before k_edge1 writes h2h.
    char* regionX = alloc((size_t)NN * C2 * 2 + (size_t)NN * 8 + 512);
    int* binned = (int*)regionX;
    __half* h2h = (__half*)regionX;
    float* als2 = (float*)(regionX + (size_t)NN * C2 * 2);
    float* ald2 = (float*)(regionX + (size_t)NN * C2 * 2 + (size_t)NN * 4);
    (void)ws_size;

    hipMemsetAsync(bhist, 0, NB * 4, stream);

    k_gemm1_chist<<<NGEMM + NCHIST, 256, 0, stream>>>(x, W1, as1, ad1, h1h, als1, ald1,
                                                      ei, bhist);
    k_bscan<<<1, 256, 0, stream>>>(bhist, gbase, gcur);
    k_bin<<<NCHIST, 256, 0, stream>>>(ei, gcur, binned);
    k_bsort<<<(NN + 127) / 128, 256, 0, stream>>>(binned, gbase, bhist, rs, deg, csr);

    k_edge1<<<NN / 4, 256, 0, stream>>>(csr, rs, deg, h1h, als1, ald1, b1, W2, as2, ad2,
                                        h2h, als2, ald2);
    k_edge2<<<NN / 4, 256, 0, stream>>>(csr, rs, deg, h2h, als2, ald2, b2, out);
}

// Round 8
// 292.960 us; speedup vs baseline: 1.2622x; 1.1343x over previous
//
#include <hip/hip_runtime.h>
#include <hip/hip_fp16.h>
#include <math.h>

#define NN 100000
#define EE 1600000
#define DIN 128
#define C1 64   // HEADS*HID
#define C2 32   // D_OUT
#define NEG 0.2f

#define NB 1024   // coarse buckets
#define BSH 7     // bucket = dst >> 7 (128 nodes per bucket)
#define EPB 4096  // edges per binning block
#define NGEMM 1563   // ceil(NN/64)
#define NCHIST 391   // ceil(EE/EPB)

static __device__ __forceinline__ float leaky(float x) { return fmaxf(x, NEG * x); }

// ---------------- fused GEMM1 + coarse histogram ----------------
__global__ __launch_bounds__(256, 2) void k_gemm1_chist(
    const float* __restrict__ x, const float* __restrict__ W1,
    const float* __restrict__ a_s, const float* __restrict__ a_d,
    __half* __restrict__ h1h, float* __restrict__ als, float* __restrict__ ald,
    const int* __restrict__ ei, int* __restrict__ bhist) {
    __shared__ float xs[64 * 128];   // 32 KB
    __shared__ float wsh[128 * 64];  // 32 KB
    int t = threadIdx.x;
    if (blockIdx.x >= NGEMM) {
        // ---- chist branch (reuses xs as int histogram) ----
        int* h = (int*)xs;
        for (int i = t; i < NB; i += 256) h[i] = 0;
        __syncthreads();
        const int4* d4p = (const int4*)(ei + EE);
        int i40 = (blockIdx.x - NGEMM) * (EPB / 4);
#pragma unroll
        for (int j = 0; j < 4; j++) {
            int idx = i40 + t + 256 * j;
            if (idx < EE / 4) {
                int4 d4 = d4p[idx];
                atomicAdd(&h[d4.x >> BSH], 1);
                atomicAdd(&h[d4.y >> BSH], 1);
                atomicAdd(&h[d4.z >> BSH], 1);
                atomicAdd(&h[d4.w >> BSH], 1);
            }
        }
        __syncthreads();
        for (int i = t; i < NB; i += 256) {
            int c = h[i];
            if (c) atomicAdd(&bhist[i], c);
        }
        return;
    }
    // ---- gemm1 branch ----
    int base = blockIdx.x * 64;
    for (int i = t; i < 2048; i += 256) ((float4*)wsh)[i] = ((const float4*)W1)[i];
    int maxn = NN - base;
    if (maxn > 64) maxn = 64;
    for (int i = t; i < 2048; i += 256) {
        int flat = i * 4;
        int n = flat >> 7;
        if (n < maxn) *(float4*)&xs[flat] = *(const float4*)&x[(size_t)(base + n) * 128 + (flat & 127)];
    }
    __syncthreads();
    int w = t >> 6, c = t & 63;
    int nb = w * 16;
    float acc[16];
#pragma unroll
    for (int j = 0; j < 16; j++) acc[j] = 0.f;
    for (int k = 0; k < 128; k += 4) {
        float w0 = wsh[k * 64 + c], w1 = wsh[(k + 1) * 64 + c];
        float w2 = wsh[(k + 2) * 64 + c], w3 = wsh[(k + 3) * 64 + c];
#pragma unroll
        for (int j = 0; j < 16; j++) {
            float4 xv = *(float4*)&xs[(nb + j) * 128 + k];
            acc[j] = fmaf(xv.x, w0, acc[j]);
            acc[j] = fmaf(xv.y, w1, acc[j]);
            acc[j] = fmaf(xv.z, w2, acc[j]);
            acc[j] = fmaf(xv.w, w3, acc[j]);
        }
    }
    float s_a = a_s[c], d_a = a_d[c];
    int hd = c >> 4;
#pragma unroll
    for (int j = 0; j < 16; j++) {
        int n = base + nb + j;
        float v = acc[j];
        float vs = v * s_a, vd = v * d_a;
#pragma unroll
        for (int off = 1; off < 16; off <<= 1) {
            vs += __shfl_xor(vs, off, 64);
            vd += __shfl_xor(vd, off, 64);
        }
        if (n < NN) {
            h1h[(size_t)n * 64 + c] = __float2half(v);
            if ((c & 15) == 0) {
                als[n * 4 + hd] = vs;
                ald[n * 4 + hd] = vd;
            }
        }
    }
}

// ---------------- rest of CSR build ----------------

__global__ __launch_bounds__(256) void k_bscan(const int* __restrict__ bhist,
                                               int* __restrict__ gbase, int* __restrict__ gcur) {
    __shared__ int s[256];
    int t = threadIdx.x;
    int base = t * 4;
    int v[4];
    int run = 0;
#pragma unroll
    for (int j = 0; j < 4; j++) {
        v[j] = run;
        run += bhist[base + j];
    }
    int val = run;
    s[t] = val;
    __syncthreads();
    for (int off = 1; off < 256; off <<= 1) {
        int add = (t >= off) ? s[t - off] : 0;
        __syncthreads();
        val += add;
        s[t] = val;
        __syncthreads();
    }
    int texcl = val - run;
#pragma unroll
    for (int j = 0; j < 4; j++) {
        gbase[base + j] = texcl + v[j];
        gcur[base + j] = texcl + v[j];
    }
}

// binned entry: (src << 7) | (dst & 127)
__global__ __launch_bounds__(256) void k_bin(const int* __restrict__ ei, int* __restrict__ gcur,
                                             int* __restrict__ binned) {
    __shared__ int h[NB];
    __shared__ int base[NB];
    int t = threadIdx.x;
    for (int i = t; i < NB; i += 256) h[i] = 0;
    __syncthreads();
    const int4* s4p = (const int4*)ei;
    const int4* d4p = (const int4*)(ei + EE);
    int i40 = blockIdx.x * (EPB / 4);
    int4 s4[4], d4[4];
    bool val[4];
#pragma unroll
    for (int j = 0; j < 4; j++) {
        int idx = i40 + t + 256 * j;
        val[j] = idx < EE / 4;
        if (val[j]) {
            s4[j] = s4p[idx];
            d4[j] = d4p[idx];
            atomicAdd(&h[d4[j].x >> BSH], 1);
            atomicAdd(&h[d4[j].y >> BSH], 1);
            atomicAdd(&h[d4[j].z >> BSH], 1);
            atomicAdd(&h[d4[j].w >> BSH], 1);
        }
    }
    __syncthreads();
    for (int i = t; i < NB; i += 256) {
        int c = h[i];
        if (c) base[i] = atomicAdd(&gcur[i], c);
        h[i] = 0;  // reuse as local cursor
    }
    __syncthreads();
#pragma unroll
    for (int j = 0; j < 4; j++) {
        if (val[j]) {
            int ss[4] = {s4[j].x, s4[j].y, s4[j].z, s4[j].w};
            int dd[4] = {d4[j].x, d4[j].y, d4[j].z, d4[j].w};
#pragma unroll
            for (int q = 0; q < 4; q++) {
                int b = dd[q] >> BSH;
                int r = atomicAdd(&h[b], 1);
                binned[base[b] + r] = (ss[q] << 7) | (dd[q] & 127);
            }
        }
    }
}

// one block per bucket: counting sort; writes rsdeg (packed) and csr
__global__ __launch_bounds__(256) void k_bsort(const int* __restrict__ binned,
                                               const int* __restrict__ gbase,
                                               const int* __restrict__ bhist,
                                               int2* __restrict__ rsdeg,
                                               int* __restrict__ csr) {
    __shared__ int h[128], cur[128], sc[128];
    int b = blockIdx.x, t = threadIdx.x;
    if (t < 128) h[t] = 0;
    __syncthreads();
    int gb = gbase[b], cnt = bhist[b];
    for (int i = t; i < cnt; i += 256) atomicAdd(&h[binned[gb + i] & 127], 1);
    __syncthreads();
    if (t < 128) sc[t] = h[t];
    __syncthreads();
    for (int off = 1; off < 128; off <<= 1) {
        int add = 0;
        if (t < 128 && t >= off) add = sc[t - off];
        __syncthreads();
        if (t < 128) sc[t] += add;
        __syncthreads();
    }
    if (t < 128) {
        int node = b * 128 + t;
        int excl = sc[t] - h[t];
        if (node < NN) rsdeg[node] = make_int2(gb + excl, h[t]);
        cur[t] = excl;
    }
    __syncthreads();
    for (int i = t; i < cnt; i += 256) {
        int e = binned[gb + i];
        int r = atomicAdd(&cur[e & 127], 1);
        csr[gb + r] = e >> 7;
    }
}

// ---------------- Edge pass 1 + fused GEMM2: 2 nodes per wave ----------------
// Each 32-lane half owns one node; lane ln = channel-pair (half2). Every lane
// walks all of its node's edges -> z/acc complete per-lane, no reduces.
__global__ __launch_bounds__(256, 4) void k_edge1(
    const int* __restrict__ csr, const int2* __restrict__ rsdeg,
    const __half* __restrict__ h1h, const float* __restrict__ als, const float* __restrict__ ald,
    const float* __restrict__ b1, const float* __restrict__ W2,
    const float* __restrict__ as2, const float* __restrict__ ad2,
    __half* __restrict__ h2h, float* __restrict__ als2, float* __restrict__ ald2) {
    __shared__ float wsh[32][68];        // W2 transposed, padded (8704 B)
    __shared__ float xld[4][2][64];      // per-node x2 row (2048 B)
    __shared__ float2 epl[4][2][4][33];  // [wave][half][head][edge]: {src_byte, p} (8448 B)
    int t = threadIdx.x;
    for (int i = t; i < 2048; i += 256) wsh[i & 31][i >> 5] = W2[i];  // transpose store
    int w = t >> 6, lane = t & 63, half = lane >> 5, ln = lane & 31;
    int n = blockIdx.x * 8 + w * 2 + half;  // NN % 8 == 0
    float4 ad4 = *(const float4*)&ald[n * 4];
    float4 an4 = *(const float4*)&als[n * 4];
    float ls0 = leaky(an4.x + ad4.x), ls1 = leaky(an4.y + ad4.y);
    float ls2 = leaky(an4.z + ad4.z), ls3 = leaky(an4.w + ad4.w);
    const __half2* h1p = (const __half2*)h1h;
    const char* h1c = (const char*)h1h;
    int hd2 = ln >> 3;       // head of channels 2ln, 2ln+1
    int coff = ln * 4;       // byte offset of half2 #ln within a row
    float2 fs = __half22float2(h1p[n * 32 + ln]);  // self contribution
    float z = 1.f, acc0 = fs.x, acc1 = fs.y;
    int2 rd = rsdeg[n];
    int s0 = rd.x, d = rd.y;
    for (int i0 = 0; i0 < d; i0 += 32) {
        // phase A: lane = edge (32 edges per node-group)
        int e = i0 + ln;
        int src = 0;
        float4 a4 = make_float4(-1e30f, -1e30f, -1e30f, -1e30f);
        if (e < d) {
            src = csr[s0 + e];
            a4 = *(const float4*)&als[src * 4];
        }
        float fsb = __int_as_float(src << 7);  // byte offset of h1 row (128 B)
        epl[w][half][0][ln] = make_float2(fsb, __expf(leaky(a4.x + ad4.x) - ls0));
        epl[w][half][1][ln] = make_float2(fsb, __expf(leaky(a4.y + ad4.y) - ls1));
        epl[w][half][2][ln] = make_float2(fsb, __expf(leaky(a4.z + ad4.z) - ls2));
        epl[w][half][3][ln] = make_float2(fsb, __expf(leaky(a4.w + ad4.w) - ls3));
        int cnt = d - i0;
        if (cnt > 32) cnt = 32;
        // phase B: every lane processes all edges of its node, 8-deep batches
        const float2* ep = epl[w][half][hd2];
        int i = 0;
        for (; i + 7 < cnt; i += 8) {
            float2 q0 = ep[i], q1 = ep[i + 1], q2 = ep[i + 2], q3 = ep[i + 3];
            float2 q4 = ep[i + 4], q5 = ep[i + 5], q6 = ep[i + 6], q7 = ep[i + 7];
            float2 f0 = __half22float2(*(const __half2*)(h1c + __float_as_int(q0.x) + coff));
            float2 f1 = __half22float2(*(const __half2*)(h1c + __float_as_int(q1.x) + coff));
            float2 f2 = __half22float2(*(const __half2*)(h1c + __float_as_int(q2.x) + coff));
            float2 f3 = __half22float2(*(const __half2*)(h1c + __float_as_int(q3.x) + coff));
            float2 f4 = __half22float2(*(const __half2*)(h1c + __float_as_int(q4.x) + coff));
            float2 f5 = __half22float2(*(const __half2*)(h1c + __float_as_int(q5.x) + coff));
            float2 f6 = __half22float2(*(const __half2*)(h1c + __float_as_int(q6.x) + coff));
            float2 f7 = __half22float2(*(const __half2*)(h1c + __float_as_int(q7.x) + coff));
            z += ((q0.y + q1.y) + (q2.y + q3.y)) + ((q4.y + q5.y) + (q6.y + q7.y));
            acc0 = fmaf(q0.y, f0.x, acc0); acc1 = fmaf(q0.y, f0.y, acc1);
            acc0 = fmaf(q1.y, f1.x, acc0); acc1 = fmaf(q1.y, f1.y, acc1);
            acc0 = fmaf(q2.y, f2.x, acc0); acc1 = fmaf(q2.y, f2.y, acc1);
            acc0 = fmaf(q3.y, f3.x, acc0); acc1 = fmaf(q3.y, f3.y, acc1);
            acc0 = fmaf(q4.y, f4.x, acc0); acc1 = fmaf(q4.y, f4.y, acc1);
            acc0 = fmaf(q5.y, f5.x, acc0); acc1 = fmaf(q5.y, f5.y, acc1);
            acc0 = fmaf(q6.y, f6.x, acc0); acc1 = fmaf(q6.y, f6.y, acc1);
            acc0 = fmaf(q7.y, f7.x, acc0); acc1 = fmaf(q7.y, f7.y, acc1);
        }
        for (; i + 3 < cnt; i += 4) {
            float2 q0 = ep[i], q1 = ep[i + 1], q2 = ep[i + 2], q3 = ep[i + 3];
            float2 f0 = __half22float2(*(const __half2*)(h1c + __float_as_int(q0.x) + coff));
            float2 f1 = __half22float2(*(const __half2*)(h1c + __float_as_int(q1.x) + coff));
            float2 f2 = __half22float2(*(const __half2*)(h1c + __float_as_int(q2.x) + coff));
            float2 f3 = __half22float2(*(const __half2*)(h1c + __float_as_int(q3.x) + coff));
            z += (q0.y + q1.y) + (q2.y + q3.y);
            acc0 = fmaf(q0.y, f0.x, acc0); acc1 = fmaf(q0.y, f0.y, acc1);
            acc0 = fmaf(q1.y, f1.x, acc0); acc1 = fmaf(q1.y, f1.y, acc1);
            acc0 = fmaf(q2.y, f2.x, acc0); acc1 = fmaf(q2.y, f2.y, acc1);
            acc0 = fmaf(q3.y, f3.x, acc0); acc1 = fmaf(q3.y, f3.y, acc1);
        }
        for (; i < cnt; i++) {
            float2 q = ep[i];
            float2 f = __half22float2(*(const __half2*)(h1c + __float_as_int(q.x) + coff));
            z += q.y;
            acc0 = fmaf(q.y, f.x, acc0);
            acc1 = fmaf(q.y, f.y, acc1);
        }
    }
    float zi = __frcp_rn(z + 1e-16f);
    float o0 = acc0 * zi + b1[2 * ln];
    float o1 = acc1 * zi + b1[2 * ln + 1];
    float xv0 = o0 > 0.f ? o0 : __expf(o0) - 1.f;  // ELU
    float xv1 = o1 > 0.f ? o1 : __expf(o1) - 1.f;
    xld[w][half][2 * ln] = xv0;
    xld[w][half][2 * ln + 1] = xv1;
    __syncthreads();  // wsh (W2T) ready; xld is wave-lockstep

    // ---- fused GEMM2: lane ln computes full column ln via b128 reads ----
    float accn = 0.f;
#pragma unroll
    for (int k4 = 0; k4 < 16; k4++) {
        float4 xk = *(float4*)&xld[w][half][k4 * 4];  // broadcast within group
        float4 wk = *(float4*)&wsh[ln][k4 * 4];
        accn = fmaf(xk.x, wk.x, accn);
        accn = fmaf(xk.y, wk.y, accn);
        accn = fmaf(xk.z, wk.z, accn);
        accn = fmaf(xk.w, wk.w, accn);
    }
    h2h[(size_t)n * 32 + ln] = __float2half(accn);
    float vs = accn * as2[ln], vd = accn * ad2[ln];
#pragma unroll
    for (int off = 1; off < 32; off <<= 1) {  // stays within 32-lane half
        vs += __shfl_xor(vs, off, 64);
        vd += __shfl_xor(vd, off, 64);
    }
    if (ln == 0) {
        als2[n] = vs;
        ald2[n] = vd;
    }
}

// ---------------- Edge pass 2: 4 nodes per wave (16 lanes each) ----------------
__global__ __launch_bounds__(256, 4) void k_edge2(
    const int* __restrict__ csr, const int2* __restrict__ rsdeg,
    const __half* __restrict__ h2h, const float* __restrict__ als, const float* __restrict__ ald,
    const float* __restrict__ b2, float* __restrict__ out) {
    __shared__ float2 pst[4][4][17];  // [wave][node-quarter][edge]: {src_byte, p}
    int t = threadIdx.x;
    int w = t >> 6, lane = t & 63, q = lane >> 4, ln = lane & 15;
    int n = blockIdx.x * 16 + w * 4 + q;  // NN % 16 == 0
    float ad = ald[n];
    float lself = leaky(als[n] + ad);
    const __half2* h2p = (const __half2*)h2h;
    const char* h2c = (const char*)h2h;
    int coff = ln * 4;
    float2 fs = __half22float2(h2p[n * 16 + ln]);
    float z = 1.f, acc0 = fs.x, acc1 = fs.y;
    int2 rd = rsdeg[n];
    int s0 = rd.x, d = rd.y;
    for (int i0 = 0; i0 < d; i0 += 16) {
        int e = i0 + ln;
        int src = 0;
        float av = -1e30f;
        if (e < d) {
            src = csr[s0 + e];
            av = als[src];
        }
        pst[w][q][ln] = make_float2(__int_as_float(src << 6),  // h2 row = 64 B
                                    __expf(leaky(av + ad) - lself));
        int cnt = d - i0;
        if (cnt > 16) cnt = 16;
        const float2* ep = pst[w][q];
        int i = 0;
        for (; i + 3 < cnt; i += 4) {
            float2 q0 = ep[i], q1 = ep[i + 1], q2 = ep[i + 2], q3 = ep[i + 3];
            float2 f0 = __half22float2(*(const __half2*)(h2c + __float_as_int(q0.x) + coff));
            float2 f1 = __half22float2(*(const __half2*)(h2c + __float_as_int(q1.x) + coff));
            float2 f2 = __half22float2(*(const __half2*)(h2c + __float_as_int(q2.x) + coff));
            float2 f3 = __half22float2(*(const __half2*)(h2c + __float_as_int(q3.x) + coff));
            z += (q0.y + q1.y) + (q2.y + q3.y);
            acc0 = fmaf(q0.y, f0.x, acc0); acc1 = fmaf(q0.y, f0.y, acc1);
            acc0 = fmaf(q1.y, f1.x, acc0); acc1 = fmaf(q1.y, f1.y, acc1);
            acc0 = fmaf(q2.y, f2.x, acc0); acc1 = fmaf(q2.y, f2.y, acc1);
            acc0 = fmaf(q3.y, f3.x, acc0); acc1 = fmaf(q3.y, f3.y, acc1);
        }
        for (; i < cnt; i++) {
            float2 qq = ep[i];
            float2 f = __half22float2(*(const __half2*)(h2c + __float_as_int(qq.x) + coff));
            z += qq.y;
            acc0 = fmaf(qq.y, f.x, acc0);
            acc1 = fmaf(qq.y, f.y, acc1);
        }
    }
    float zi = __frcp_rn(z + 1e-16f);
    float o0 = acc0 * zi + b2[2 * ln];
    float o1 = acc1 * zi + b2[2 * ln + 1];
    *(float2*)&out[(size_t)n * 32 + 2 * ln] = make_float2(o0, o1);
}

// ---------------- launcher ----------------
extern "C" void kernel_launch(void* const* d_in, const int* in_sizes, int n_in,
                              void* d_out, int out_size, void* d_ws, size_t ws_size,
                              hipStream_t stream) {
    const float* x = (const float*)d_in[0];
    const int* ei = (const int*)d_in[1];
    const float* W1 = (const float*)d_in[2];
    const float* as1 = (const float*)d_in[3];
    const float* ad1 = (const float*)d_in[4];
    const float* b1 = (const float*)d_in[5];
    const float* W2 = (const float*)d_in[6];
    const float* as2 = (const float*)d_in[7];
    const float* ad2 = (const float*)d_in[8];
    const float* b2 = (const float*)d_in[9];
    float* out = (float*)d_out;

    char* p = (char*)d_ws;
    auto alloc = [&](size_t bytes) -> char* {
        char* r = p;
        p += (bytes + 255) & ~(size_t)255;
        return r;
    };
    int* csr = (int*)alloc((size_t)EE * 4);
    int2* rsdeg = (int2*)alloc((size_t)NN * 8);
    int* bhist = (int*)alloc(NB * 4);
    int* gbase = (int*)alloc(NB * 4);
    int* gcur = (int*)alloc(NB * 4);
    __half* h1h = (__half*)alloc((size_t)NN * C1 * 2);
    float* als1 = (float*)alloc((size_t)NN * 4 * 4);
    float* ald1 = (float*)alloc((size_t)NN * 4 * 4);
    // region X: binned (6.4 MB) aliases h2h/als2/ald2 (7.2 MB); binned dead
    // before k_edge1 writes h2h.
    char* regionX = alloc((size_t)NN * C2 * 2 + (size_t)NN * 8 + 512);
    int* binned = (int*)regionX;
    __half* h2h = (__half*)regionX;
    float* als2 = (float*)(regionX + (size_t)NN * C2 * 2);
    float* ald2 = (float*)(regionX + (size_t)NN * C2 * 2 + (size_t)NN * 4);
    (void)ws_size;

    hipMemsetAsync(bhist, 0, NB * 4, stream);

    k_gemm1_chist<<<NGEMM + NCHIST, 256, 0, stream>>>(x, W1, as1, ad1, h1h, als1, ald1,
                                                      ei, bhist);
    k_bscan<<<1, 256, 0, stream>>>(bhist, gbase, gcur);
    k_bin<<<NCHIST, 256, 0, stream>>>(ei, gcur, binned);
    k_bsort<<<(NN + 127) / 128, 256, 0, stream>>>(binned, gbase, bhist, rsdeg, csr);

    k_edge1<<<NN / 8, 256, 0, stream>>>(csr, rsdeg, h1h, als1, ald1, b1, W2, as2, ad2,
                                        h2h, als2, ald2);
    k_edge2<<<NN / 16, 256, 0, stream>>>(csr, rsdeg, h2h, als2, ald2, b2, out);
}